// Round 13
// baseline (90.280 us; speedup 1.0000x reference)
//
#include <hip/hip_runtime.h>

#define N_NODES 10000
#define N_EDGES 320000
#define DIN 256
#define DOUT 256
#define SLOTS 96   // max-degree slack: Binom(320K,1e-4) mean 32, sigma 5.7 -> +11 sigma
#define LDA 264    // LDS A-tile row stride (ushorts)

typedef short bf16x8 __attribute__((ext_vector_type(8)));
typedef float f32x4 __attribute__((ext_vector_type(4)));

__device__ __forceinline__ unsigned bfrne(float f) {  // f32 -> bf16 bits (RNE)
    unsigned u = __float_as_uint(f);
    return (u + 0x7fffu + ((u >> 16) & 1u)) >> 16;
}
__device__ __forceinline__ float blo(unsigned u) { return __uint_as_float(u << 16); }
__device__ __forceinline__ float bhi(unsigned u) { return __uint_as_float(u & 0xffff0000u); }

// ---------- K1: xb = bf16(x), Wt = bf16(W^T), deg = deg2 = 0 ----------
#define NX4 (N_NODES * 64)  // 640000 x-quads
#define NW4 (DIN * 64)      // 16384 W-quads
#define PREP_TOTAL (NX4 + NW4 + 2 * N_NODES)
__global__ __launch_bounds__(256) void prep_kernel(
    const float4* __restrict__ x4, const float4* __restrict__ W4,
    uint2* __restrict__ xb4, ushort* __restrict__ Wt, int* __restrict__ deg,
    int* __restrict__ deg2) {
    int g = blockIdx.x * blockDim.x + threadIdx.x;
    if (g < NX4) {
        float4 v = x4[g];
        uint2 o;
        o.x = bfrne(v.x) | (bfrne(v.y) << 16);
        o.y = bfrne(v.z) | (bfrne(v.w) << 16);
        xb4[g] = o;
    } else if (g < NX4 + NW4) {
        int g3 = g - NX4;
        int k = g3 >> 6;
        int c0 = (g3 & 63) * 4;
        float4 w = W4[g3];  // W[k][c0..c0+3], coalesced
        Wt[(c0 + 0) * DIN + k] = (ushort)bfrne(w.x);
        Wt[(c0 + 1) * DIN + k] = (ushort)bfrne(w.y);
        Wt[(c0 + 2) * DIN + k] = (ushort)bfrne(w.z);
        Wt[(c0 + 3) * DIN + k] = (ushort)bfrne(w.w);
    } else if (g < NX4 + NW4 + N_NODES) {
        deg[g - NX4 - NW4] = 0;
    } else if (g < PREP_TOTAL) {
        deg2[g - NX4 - NW4 - N_NODES] = 0;
    }
}

// ---------- K2a (DECOY, measurement): old 1-edge/thread count+fill -> scratch ----------
__global__ __launch_bounds__(256) void count_fill_kernel(
    const int* __restrict__ src, const int* __restrict__ dst,
    int* __restrict__ deg, int* __restrict__ slot) {
    int e = blockIdx.x * blockDim.x + threadIdx.x;
    if (e < N_EDGES) {
        int s = src[e];
        int p = atomicAdd(&deg[s], 1);
        if (p < SLOTS) slot[s * SLOTS + p] = dst[e];
    }
}

// ---------- K2b (REAL): 4 edges/thread, 4 independent atomic chains (MLP=4) ----------
__global__ __launch_bounds__(256) void count_fill4_kernel(
    const int4* __restrict__ src4, const int4* __restrict__ dst4,
    int* __restrict__ deg, int* __restrict__ slot) {
    int t = blockIdx.x * blockDim.x + threadIdx.x;
    if (t < N_EDGES / 4) {
        int4 s = src4[t];
        int4 d = dst4[t];
        int p0 = atomicAdd(&deg[s.x], 1);
        int p1 = atomicAdd(&deg[s.y], 1);
        int p2 = atomicAdd(&deg[s.z], 1);
        int p3 = atomicAdd(&deg[s.w], 1);
        if (p0 < SLOTS) slot[s.x * SLOTS + p0] = d.x;
        if (p1 < SLOTS) slot[s.y * SLOTS + p1] = d.y;
        if (p2 < SLOTS) slot[s.z * SLOTS + p2] = d.z;
        if (p3 < SLOTS) slot[s.w * SLOTS + p3] = d.w;
    }
}

// ---------- K3: fused aggregate (node-per-HALF-wave) + MFMA GEMM (round-12 best) ----------
__global__ __launch_bounds__(512, 8) void agg_gemm_kernel(
    const uint4* __restrict__ xbq, const int* __restrict__ deg,
    const int* __restrict__ slot, const ushort* __restrict__ Wt,
    const float* __restrict__ bias, float* __restrict__ out) {
    __shared__ ushort sA[16 * LDA];  // 8448 B

    const int tid = threadIdx.x;
    const int w = tid >> 6;
    const int lane = tid & 63;
    const int half = lane >> 5;  // which node of the wave's pair
    const int hl = lane & 31;    // channel group: ch [hl*8, hl*8+8)
    const int row = w * 2 + half;
    const int node = blockIdx.x * 16 + row;

    int dg = deg[node];
    float di = rsqrtf((float)dg);
    int dgc = min(dg, SLOTS);
    int base = node * SLOTS;

    // preload this node's neighbor list into the half's 32 lanes (3 x 32 slots)
    int jA = 0; float vA = 0.f;
    if (hl < dgc) { jA = slot[base + hl]; vA = rsqrtf((float)deg[jA]); }
    int jB = 0; float vB = 0.f;
    if (32 + hl < dgc) { jB = slot[base + 32 + hl]; vB = rsqrtf((float)deg[jB]); }
    int jC = 0; float vC = 0.f;
    if (64 + hl < dgc) { jC = slot[base + 64 + hl]; vC = rsqrtf((float)deg[jC]); }

    float a0 = 0.f, a1 = 0.f, a2 = 0.f, a3 = 0.f,
          a4 = 0.f, a5 = 0.f, a6 = 0.f, a7 = 0.f;

#define FETCH(t_, j_, d_) {                                          \
    int srcl_ = half * 32 + ((t_) & 31);                             \
    int sel_ = (t_) >> 5;                                            \
    if (sel_ == 0)      { j_ = __shfl(jA, srcl_, 64); d_ = __shfl(vA, srcl_, 64); } \
    else if (sel_ == 1) { j_ = __shfl(jB, srcl_, 64); d_ = __shfl(vB, srcl_, 64); } \
    else                { j_ = __shfl(jC, srcl_, 64); d_ = __shfl(vC, srcl_, 64); } \
}
#define ACC(c_, d_) {                                      \
    a0 += (d_) * blo((c_).x); a1 += (d_) * bhi((c_).x);    \
    a2 += (d_) * blo((c_).y); a3 += (d_) * bhi((c_).y);    \
    a4 += (d_) * blo((c_).z); a5 += (d_) * bhi((c_).z);    \
    a6 += (d_) * blo((c_).w); a7 += (d_) * bhi((c_).w);    \
}

    if (dgc > 0) {
        int j0; float d0;
        FETCH(0, j0, d0);
        uint4 c0 = xbq[j0 * 32 + hl];
        for (int t = 1; t < dgc; ++t) {
            int j1; float d1;
            FETCH(t, j1, d1);
            uint4 c1 = xbq[j1 * 32 + hl];  // issue before consuming c0
            ACC(c0, d0);
            c0 = c1; d0 = d1;
        }
        ACC(c0, d0);
    }

    // self term + final scale: agg = di*(sum + di*self); channels are lane-exclusive
    uint4 sv = xbq[node * 32 + hl];
    a0 = di * (a0 + di * blo(sv.x)); a1 = di * (a1 + di * bhi(sv.x));
    a2 = di * (a2 + di * blo(sv.y)); a3 = di * (a3 + di * bhi(sv.y));
    a4 = di * (a4 + di * blo(sv.z)); a5 = di * (a5 + di * bhi(sv.z));
    a6 = di * (a6 + di * blo(sv.w)); a7 = di * (a7 + di * bhi(sv.w));

    uint4 o;
    o.x = bfrne(a0) | (bfrne(a1) << 16);
    o.y = bfrne(a2) | (bfrne(a3) << 16);
    o.z = bfrne(a4) | (bfrne(a5) << 16);
    o.w = bfrne(a6) | (bfrne(a7) << 16);
    *(uint4*)&sA[row * LDA + hl * 8] = o;

    __syncthreads();

    // ---- Phase B: wave w computes out cols [w*32, w*32+32) for the 16 rows ----
    int r = lane & 15;
    int gq = lane >> 4;
    const ushort* wp0 = Wt + (w * 32 + r) * DIN;
    const ushort* wp1 = Wt + (w * 32 + 16 + r) * DIN;
    f32x4 acc0 = {0.f, 0.f, 0.f, 0.f};
    f32x4 acc1 = {0.f, 0.f, 0.f, 0.f};
#pragma unroll
    for (int k8 = 0; k8 < 8; ++k8) {
        int koff = k8 * 32 + gq * 8;
        bf16x8 a = *(const bf16x8*)&sA[r * LDA + koff];
        acc0 = __builtin_amdgcn_mfma_f32_16x16x32_bf16(a, *(const bf16x8*)(wp0 + koff), acc0, 0, 0, 0);
        acc1 = __builtin_amdgcn_mfma_f32_16x16x32_bf16(a, *(const bf16x8*)(wp1 + koff), acc1, 0, 0, 0);
    }

    int rbase = blockIdx.x * 16 + gq * 4;
    int oc0 = w * 32 + r;
    int oc1 = oc0 + 16;
    float bv0 = bias[oc0];
    float bv1 = bias[oc1];
#pragma unroll
    for (int i = 0; i < 4; ++i) {
        out[(rbase + i) * DOUT + oc0] = fmaxf(acc0[i] + bv0, 0.f);
        out[(rbase + i) * DOUT + oc1] = fmaxf(acc1[i] + bv1, 0.f);
    }
}

extern "C" void kernel_launch(void* const* d_in, const int* in_sizes, int n_in,
                              void* d_out, int out_size, void* d_ws, size_t ws_size,
                              hipStream_t stream) {
    const float* x = (const float*)d_in[0];
    const int* edge_index = (const int*)d_in[1];
    const float* W = (const float*)d_in[2];
    const float* b = (const float*)d_in[3];
    float* out = (float*)d_out;

    const int* src = edge_index;            // edge_index[0, :]
    const int* dst = edge_index + N_EDGES;  // edge_index[1, :]

    char* ws = (char*)d_ws;
    int* deg     = (int*)(ws + 0);          // 40,000 B
    int* slot    = (int*)(ws + 40064);      // 3,840,000 B (10000 x 96 ints)
    ushort* xb   = (ushort*)(ws + 3880064); // 5,120,000 B (bf16 10000 x 256)
    ushort* Wt   = (ushort*)(ws + 9000064); // 131,072 B  (bf16 256x256 transposed)
    int* deg2    = (int*)(ws + 9131136);    // 40,000 B  (decoy)
    int* slot2   = (int*)(ws + 9171200);    // 3,840,000 B (decoy) -> ~13.0 MB total

    prep_kernel<<<(PREP_TOTAL + 255) / 256, 256, 0, stream>>>(
        (const float4*)x, (const float4*)W, (uint2*)xb, Wt, deg, deg2);
    // decoy (measurement): old count_fill into scratch — its duration shows up in dur_us delta
    count_fill_kernel<<<N_EDGES / 256, 256, 0, stream>>>(src, dst, deg2, slot2);
    // real: 4-edge/thread MLP variant
    count_fill4_kernel<<<(N_EDGES / 4 + 255) / 256, 256, 0, stream>>>(
        (const int4*)src, (const int4*)dst, deg, slot);
    agg_gemm_kernel<<<N_NODES / 16, 512, 0, stream>>>(
        (const uint4*)xb, deg, slot, Wt, b, out);
}

// Round 14
// 70.949 us; speedup vs baseline: 1.2725x; 1.2725x over previous
//
#include <hip/hip_runtime.h>

#define N_NODES 10000
#define N_EDGES 320000
#define DIN 256
#define DOUT 256
#define SLOTS 96   // max-degree slack: Binom(320K,1e-4) mean 32, sigma 5.7 -> +11 sigma
#define LDA 264    // LDS A-tile row stride (ushorts)

typedef short bf16x8 __attribute__((ext_vector_type(8)));
typedef float f32x4 __attribute__((ext_vector_type(4)));

__device__ __forceinline__ unsigned bfrne(float f) {  // f32 -> bf16 bits (RNE)
    unsigned u = __float_as_uint(f);
    return (u + 0x7fffu + ((u >> 16) & 1u)) >> 16;
}
__device__ __forceinline__ float blo(unsigned u) { return __uint_as_float(u << 16); }
__device__ __forceinline__ float bhi(unsigned u) { return __uint_as_float(u & 0xffff0000u); }

// ---------- K0: deg = 0 ----------
__global__ void zero_kernel(int* __restrict__ p, int n) {
    int i = blockIdx.x * blockDim.x + threadIdx.x;
    if (i < n) p[i] = 0;
}

// ---------- K1: fused degree-count + slot fill ----------
__global__ __launch_bounds__(256) void count_fill_kernel(
    const int* __restrict__ src, const int* __restrict__ dst,
    int* __restrict__ deg, int* __restrict__ slot) {
    int e = blockIdx.x * blockDim.x + threadIdx.x;
    if (e < N_EDGES) {
        int s = src[e];
        int p = atomicAdd(&deg[s], 1);
        if (p < SLOTS) slot[s * SLOTS + p] = dst[e];
    }
}

// ---------- K2: prep (AFTER count): xs = bf16(d_i * x_i), Wt = bf16(W^T) ----------
#define NX4 (N_NODES * 64)  // 640000 x-quads
#define NW4 (DIN * 64)      // 16384 W-quads
#define PREP_TOTAL (NX4 + NW4)
__global__ __launch_bounds__(256) void prep_kernel(
    const float4* __restrict__ x4, const float4* __restrict__ W4,
    const int* __restrict__ deg, uint2* __restrict__ xs2, ushort* __restrict__ Wt) {
    int g = blockIdx.x * blockDim.x + threadIdx.x;
    if (g < NX4) {
        int i = g >> 6;
        float di = rsqrtf((float)deg[i]);
        float4 v = x4[g];
        uint2 o;
        o.x = bfrne(di * v.x) | (bfrne(di * v.y) << 16);
        o.y = bfrne(di * v.z) | (bfrne(di * v.w) << 16);
        xs2[g] = o;
    } else if (g < PREP_TOTAL) {
        int g3 = g - NX4;
        int k = g3 >> 6;
        int c0 = (g3 & 63) * 4;
        float4 w = W4[g3];  // W[k][c0..c0+3], coalesced
        Wt[(c0 + 0) * DIN + k] = (ushort)bfrne(w.x);
        Wt[(c0 + 1) * DIN + k] = (ushort)bfrne(w.y);
        Wt[(c0 + 2) * DIN + k] = (ushort)bfrne(w.z);
        Wt[(c0 + 3) * DIN + k] = (ushort)bfrne(w.w);
    }
}

// ---------- K3: fused aggregate (wave-per-node, SCALAR neighbor addressing) + MFMA ----------
// block = 1024 thr = 16 waves = 16 nodes; 625 blocks.
// Per wave: node is wave-uniform (readfirstlane-forced) -> slot[base+t] is a
// SCALAR load (batches of 8 via s_load_dwordx8); row loads are saddr-form
// vector loads, 8 independent per unroll chunk — no shfl/LDS in the address
// chain. xs pre-scaled by d_j: inner op = unpack + add (8 VALU/edge/lane-row).
__global__ __launch_bounds__(1024, 8) void agg_gemm_kernel(
    const uint2* __restrict__ xs2, const int* __restrict__ deg,
    const int* __restrict__ slot, const ushort* __restrict__ Wt,
    const float* __restrict__ bias, float* __restrict__ out) {
    __shared__ ushort sA[16 * LDA];  // 8448 B

    const int tid = threadIdx.x;
    const int w = tid >> 6;
    const int lane = tid & 63;  // channels [lane*4, lane*4+4) via uint2
    const int node = __builtin_amdgcn_readfirstlane(blockIdx.x * 16 + w);

    int dg = deg[node];            // wave-uniform scalar load
    float di = rsqrtf((float)dg);
    int dgc = min(dg, SLOTS);
    int base = node * SLOTS;

    float a0 = 0.f, a1 = 0.f, a2 = 0.f, a3 = 0.f;

#define ACC1(c_) {                              \
    a0 += blo((c_).x); a1 += bhi((c_).x);       \
    a2 += blo((c_).y); a3 += bhi((c_).y);       \
}

    int t = 0;
    for (; t + 8 <= dgc; t += 8) {
        int j0 = slot[base + t + 0];
        int j1 = slot[base + t + 1];
        int j2 = slot[base + t + 2];
        int j3 = slot[base + t + 3];
        int j4 = slot[base + t + 4];
        int j5 = slot[base + t + 5];
        int j6 = slot[base + t + 6];
        int j7 = slot[base + t + 7];
        uint2 c0 = xs2[j0 * 64 + lane];
        uint2 c1 = xs2[j1 * 64 + lane];
        uint2 c2 = xs2[j2 * 64 + lane];
        uint2 c3 = xs2[j3 * 64 + lane];
        uint2 c4 = xs2[j4 * 64 + lane];
        uint2 c5 = xs2[j5 * 64 + lane];
        uint2 c6 = xs2[j6 * 64 + lane];
        uint2 c7 = xs2[j7 * 64 + lane];
        ACC1(c0); ACC1(c1); ACC1(c2); ACC1(c3);
        ACC1(c4); ACC1(c5); ACC1(c6); ACC1(c7);
    }
    for (; t < dgc; ++t) {
        int j = slot[base + t];
        uint2 c = xs2[j * 64 + lane];
        ACC1(c);
    }

    // self term + final scale: agg = di * (sum_j xs_j + xs_self)
    uint2 sv = xs2[node * 64 + lane];
    a0 = di * (a0 + blo(sv.x));
    a1 = di * (a1 + bhi(sv.x));
    a2 = di * (a2 + blo(sv.y));
    a3 = di * (a3 + bhi(sv.y));

    uint2 o;
    o.x = bfrne(a0) | (bfrne(a1) << 16);
    o.y = bfrne(a2) | (bfrne(a3) << 16);
    *(uint2*)&sA[w * LDA + lane * 4] = o;

    __syncthreads();

    // ---- Phase B: wave w computes out cols [w*16, w*16+16) for the 16 rows ----
    // A frag: lane holds sA[row=lane&15][k=(lane>>4)*8 ..+8)
    // B frag: lane holds Wt[col=w*16+(lane&15)][k ..+8)
    // C/D: col = lane&15, row = (lane>>4)*4 + reg
    int r = lane & 15;
    int gq = lane >> 4;
    const ushort* wp = Wt + (w * 16 + r) * DIN;
    f32x4 acc = {0.f, 0.f, 0.f, 0.f};
#pragma unroll
    for (int k8 = 0; k8 < 8; ++k8) {
        int koff = k8 * 32 + gq * 8;
        bf16x8 a = *(const bf16x8*)&sA[r * LDA + koff];
        bf16x8 b = *(const bf16x8*)(wp + koff);
        acc = __builtin_amdgcn_mfma_f32_16x16x32_bf16(a, b, acc, 0, 0, 0);
    }

    int ocol = w * 16 + r;
    float bv = bias[ocol];
    int rbase = blockIdx.x * 16 + gq * 4;
#pragma unroll
    for (int i = 0; i < 4; ++i) {
        out[(rbase + i) * DOUT + ocol] = fmaxf(acc[i] + bv, 0.f);
    }
}

extern "C" void kernel_launch(void* const* d_in, const int* in_sizes, int n_in,
                              void* d_out, int out_size, void* d_ws, size_t ws_size,
                              hipStream_t stream) {
    const float* x = (const float*)d_in[0];
    const int* edge_index = (const int*)d_in[1];
    const float* W = (const float*)d_in[2];
    const float* b = (const float*)d_in[3];
    float* out = (float*)d_out;

    const int* src = edge_index;            // edge_index[0, :]
    const int* dst = edge_index + N_EDGES;  // edge_index[1, :]

    char* ws = (char*)d_ws;
    int* deg    = (int*)(ws + 0);          // 40,000 B
    int* slot   = (int*)(ws + 40064);      // 3,840,000 B (10000 x 96 ints)
    ushort* xs  = (ushort*)(ws + 3880064); // 5,120,000 B (bf16 10000 x 256, pre-scaled by d_j)
    ushort* Wt  = (ushort*)(ws + 9000064); // 131,072 B  (bf16 256x256 transposed)

    zero_kernel<<<(N_NODES + 255) / 256, 256, 0, stream>>>(deg, N_NODES);
    count_fill_kernel<<<N_EDGES / 256, 256, 0, stream>>>(src, dst, deg, slot);
    prep_kernel<<<(PREP_TOTAL + 255) / 256, 256, 0, stream>>>(
        (const float4*)x, (const float4*)W, deg, (uint2*)xs, Wt);
    agg_gemm_kernel<<<N_NODES / 16, 1024, 0, stream>>>(
        (const uint2*)xs, deg, slot, Wt, b, out);
}